// Round 2
// baseline (382.061 us; speedup 1.0000x reference)
//
#include <hip/hip_runtime.h>

#define S_LEN 2048
#define QKV_N 3072
#define SCALE 0.125f

typedef __bf16 bf16_t;
typedef bf16_t b16x8 __attribute__((ext_vector_type(8)));
typedef unsigned short u16x8 __attribute__((ext_vector_type(8)));
typedef float f32x4 __attribute__((ext_vector_type(4)));

__device__ __forceinline__ unsigned short f2b(float f){
  unsigned int u = __builtin_bit_cast(unsigned int, f);
  u += 0x7fffu + ((u >> 16) & 1u);
  return (unsigned short)(u >> 16);
}

// ---------------- elementwise f32 -> bf16 ----------------
__global__ __launch_bounds__(256) void k_cvt(const float* __restrict__ x,
                                             unsigned short* __restrict__ y){
  int i = (blockIdx.x * 256 + threadIdx.x) * 4;
  float4 v = *reinterpret_cast<const float4*>(x + i);
  ushort4 o; o.x = f2b(v.x); o.y = f2b(v.y); o.z = f2b(v.z); o.w = f2b(v.w);
  *reinterpret_cast<ushort4*>(y + i) = o;
}

// ------- transpose f32 [2048][Ncols] -> bf16 [nOff+Ncols][2048] -------
__global__ __launch_bounds__(256) void k_transpose(const float* __restrict__ W,
                                                   unsigned short* __restrict__ Wt,
                                                   int Ncols, int nOff){
  __shared__ float t[64][65];
  int tx = threadIdx.x & 15, ty = threadIdx.x >> 4;
  int n0 = blockIdx.x * 64, k0 = blockIdx.y * 64;
#pragma unroll
  for (int s2 = 0; s2 < 4; ++s2){
    int kr = ty + s2*16;
    float4 v = *reinterpret_cast<const float4*>(W + (size_t)(k0+kr)*Ncols + n0 + tx*4);
    t[kr][tx*4+0]=v.x; t[kr][tx*4+1]=v.y; t[kr][tx*4+2]=v.z; t[kr][tx*4+3]=v.w;
  }
  __syncthreads();
#pragma unroll
  for (int s2 = 0; s2 < 4; ++s2){
    int nr = ty + s2*16;
    ushort4 o;
    o.x = f2b(t[tx*4+0][nr]); o.y = f2b(t[tx*4+1][nr]);
    o.z = f2b(t[tx*4+2][nr]); o.w = f2b(t[tx*4+3][nr]);
    *reinterpret_cast<ushort4*>(Wt + (size_t)(nOff + n0 + nr)*2048 + k0 + tx*4) = o;
  }
}

// ------- GEMM: C[M][N] f32 = A[M][K] bf16 * Bt[N][K]^T bf16 -------
__global__ __launch_bounds__(256) void k_gemm_bt(const unsigned short* __restrict__ A,
                                                const unsigned short* __restrict__ Bt,
                                                float* __restrict__ C,
                                                int M, int N, int K){
  __shared__ unsigned short As[128*40];
  __shared__ unsigned short Bs[128*40];
  const int tid = threadIdx.x, lane = tid & 63, w = tid >> 6;
  const int wr = w >> 1, wc = w & 1;
  const int l15 = lane & 15, lq = lane >> 4;
  const int rowA0 = blockIdx.y * 128, rowB0 = blockIdx.x * 128;
  const int str = tid >> 2, stc = (tid & 3) * 8;
  f32x4 acc[4][4];
  f32x4 z4 = {0.f,0.f,0.f,0.f};
#pragma unroll
  for (int m=0;m<4;++m)
#pragma unroll
    for (int n=0;n<4;++n) acc[m][n] = z4;
  for (int k0 = 0; k0 < K; k0 += 32){
    __syncthreads();
#pragma unroll
    for (int p = 0; p < 2; ++p){
      int r = p*64 + str;
      u16x8 va = *reinterpret_cast<const u16x8*>(A  + (size_t)(rowA0+r)*K + k0 + stc);
      u16x8 vb = *reinterpret_cast<const u16x8*>(Bt + (size_t)(rowB0+r)*K + k0 + stc);
      *reinterpret_cast<u16x8*>(&As[r*40 + stc]) = va;
      *reinterpret_cast<u16x8*>(&Bs[r*40 + stc]) = vb;
    }
    __syncthreads();
    b16x8 af[4], bfr[4];
#pragma unroll
    for (int m=0;m<4;++m)
      af[m] = *reinterpret_cast<const b16x8*>(&As[(wr*64 + m*16 + l15)*40 + lq*8]);
#pragma unroll
    for (int n=0;n<4;++n)
      bfr[n] = *reinterpret_cast<const b16x8*>(&Bs[(wc*64 + n*16 + l15)*40 + lq*8]);
#pragma unroll
    for (int m=0;m<4;++m)
#pragma unroll
      for (int n=0;n<4;++n)
        acc[m][n] = __builtin_amdgcn_mfma_f32_16x16x32_bf16(af[m], bfr[n], acc[m][n], 0,0,0);
  }
  const int rB = rowA0 + wr*64, cB = rowB0 + wc*64;
#pragma unroll
  for (int m=0;m<4;++m)
#pragma unroll
    for (int n=0;n<4;++n)
#pragma unroll
      for (int r=0;r<4;++r)
        C[(size_t)(rB + m*16 + lq*4 + r)*N + cB + n*16 + l15] = acc[m][n][r];
}

// ------- per-head RMSNorm (+RoPE for SWA q/k), f32 -> bf16 heads -------
__global__ __launch_bounds__(256) void k_normrope(const float* __restrict__ QKV,
    const int* __restrict__ pos, const float* __restrict__ qw, const float* __restrict__ kw,
    unsigned short* __restrict__ Qb, unsigned short* __restrict__ Kb,
    unsigned short* __restrict__ Vb){
  int job = blockIdx.x * 4 + (threadIdx.x >> 6);
  int row = blockIdx.y;
  int d = threadIdx.x & 63;
  int srcCol; unsigned short* dst; const float* wn = qw; int norm = 1, rope = 0;
  if (job < 24){ srcCol = job*64; dst = Qb + ((size_t)job*S_LEN + row)*64; rope = 1; }
  else if (job < 30){ int h=job-24; srcCol = 1536 + h*64; dst = Kb + ((size_t)h*S_LEN + row)*64; wn = kw; rope = 1; }
  else if (job < 36){ int h=job-30; srcCol = 1920 + h*64; dst = Vb + ((size_t)h*S_LEN + row)*64; norm = 0; }
  else if (job < 44){ int h=job-36; srcCol = 2304 + h*64; dst = Qb + ((size_t)(24+h)*S_LEN + row)*64; }
  else if (job < 46){ int h=job-44; srcCol = 2816 + h*64; dst = Kb + ((size_t)(6+h)*S_LEN + row)*64; wn = kw; }
  else { int h=job-46; srcCol = 2944 + h*64; dst = Vb + ((size_t)(6+h)*S_LEN + row)*64; norm = 0; }
  float x = QKV[(size_t)row*QKV_N + srcCol + d];
  float y = x;
  if (norm){
    float ss = x*x;
#pragma unroll
    for (int m=1;m<64;m<<=1) ss += __shfl_xor(ss, m);
    y = x * rsqrtf(ss*(1.0f/64.0f) + 1e-6f) * wn[d];
  }
  if (rope){
    int i = d & 31;
    float inv = expf(-(float)i * (13.815510557964274f * (1.0f/32.0f)));
    float ang = (float)pos[row] * inv;
    float c = cosf(ang), sn = sinf(ang);
    float partner = __shfl_xor(y, 32);
    y = (d < 32) ? (y*c - partner*sn) : (y*c + partner*sn);
  }
  dst[d] = f2b(y);
}

// ------- flash attention: block = (16-row q tile, kv head); 4 waves = 4 grouped q heads -------
__global__ __launch_bounds__(256) void k_attn(const unsigned short* __restrict__ Qb,
    const unsigned short* __restrict__ Kb, const unsigned short* __restrict__ Vb,
    unsigned short* __restrict__ Ob){
  __shared__ unsigned short Ks[32*72];
  __shared__ unsigned short Vt[64*40];
  __shared__ unsigned short Pl[4][16*40];
  const int tid = threadIdx.x, lane = tid & 63, w = tid >> 6;
  const int l15 = lane & 15, lq = lane >> 4;
  const int qt = blockIdx.x, kvi = blockIdx.y;
  const bool swa = (kvi < 6);
  const int win = swa ? 512 : (1 << 30);
  const int qh = swa ? (kvi*4 + w) : (24 + (kvi - 6)*4 + w);
  const int q0 = qt * 16;
  const unsigned short* Qh = Qb + ((size_t)qh*S_LEN + q0)*64;
  const unsigned short* Kh = Kb + (size_t)kvi*S_LEN*64;
  const unsigned short* Vh = Vb + (size_t)kvi*S_LEN*64;
  b16x8 qf0 = *reinterpret_cast<const b16x8*>(Qh + l15*64 + lq*8);
  b16x8 qf1 = *reinterpret_cast<const b16x8*>(Qh + l15*64 + 32 + lq*8);
  f32x4 z4 = {0.f,0.f,0.f,0.f};
  f32x4 o[4];
#pragma unroll
  for (int n=0;n<4;++n) o[n] = z4;
  float mrow[4] = {-1e30f,-1e30f,-1e30f,-1e30f};
  float lrow[4] = {0.f,0.f,0.f,0.f};
  int jstart = 0;
  if (swa){ jstart = q0 - 511; if (jstart < 0) jstart = 0; jstart &= ~31; }
  const int jend = q0 + 16;
  const int sr = tid >> 3, sc = (tid & 7)*8;
  for (int j0 = jstart; j0 < jend; j0 += 32){
    __syncthreads();
    u16x8 kv = *reinterpret_cast<const u16x8*>(Kh + (size_t)(j0+sr)*64 + sc);
    u16x8 vv = *reinterpret_cast<const u16x8*>(Vh + (size_t)(j0+sr)*64 + sc);
    *reinterpret_cast<u16x8*>(&Ks[sr*72 + sc]) = kv;
#pragma unroll
    for (int jj=0;jj<8;++jj) Vt[(sc+jj)*40 + sr] = (unsigned short)vv[jj];
    __syncthreads();
    f32x4 s[2]; s[0] = z4; s[1] = z4;
#pragma unroll
    for (int ct=0;ct<2;++ct){
      b16x8 kf0 = *reinterpret_cast<const b16x8*>(&Ks[(ct*16 + l15)*72 + lq*8]);
      b16x8 kf1 = *reinterpret_cast<const b16x8*>(&Ks[(ct*16 + l15)*72 + 32 + lq*8]);
      s[ct] = __builtin_amdgcn_mfma_f32_16x16x32_bf16(qf0, kf0, s[ct], 0,0,0);
      s[ct] = __builtin_amdgcn_mfma_f32_16x16x32_bf16(qf1, kf1, s[ct], 0,0,0);
    }
#pragma unroll
    for (int r=0;r<4;++r){
      int q = q0 + lq*4 + r;
      int jA = j0 + l15, jB = j0 + 16 + l15;
      bool vA = (jA <= q) && (q - jA < win);
      bool vB = (jB <= q) && (q - jB < win);
      float sA = vA ? s[0][r]*SCALE : -1e30f;
      float sB = vB ? s[1][r]*SCALE : -1e30f;
      float mx = fmaxf(sA, sB);
#pragma unroll
      for (int mm=1; mm<16; mm<<=1) mx = fmaxf(mx, __shfl_xor(mx, mm));
      float mnew = fmaxf(mrow[r], mx);
      float pA = vA ? __expf(sA - mnew) : 0.f;
      float pB = vB ? __expf(sB - mnew) : 0.f;
      float f = __expf(mrow[r] - mnew);
      float psum = pA + pB;
#pragma unroll
      for (int mm=1; mm<16; mm<<=1) psum += __shfl_xor(psum, mm);
      lrow[r] = lrow[r]*f + psum;
      mrow[r] = mnew;
#pragma unroll
      for (int n=0;n<4;++n) o[n][r] *= f;
      Pl[w][(lq*4 + r)*40 + l15]      = f2b(pA);
      Pl[w][(lq*4 + r)*40 + 16 + l15] = f2b(pB);
    }
    b16x8 pf = *reinterpret_cast<const b16x8*>(&Pl[w][l15*40 + lq*8]);
#pragma unroll
    for (int n=0;n<4;++n){
      b16x8 vf = *reinterpret_cast<const b16x8*>(&Vt[(n*16 + l15)*40 + lq*8]);
      o[n] = __builtin_amdgcn_mfma_f32_16x16x32_bf16(pf, vf, o[n], 0,0,0);
    }
  }
#pragma unroll
  for (int n=0;n<4;++n)
#pragma unroll
    for (int r=0;r<4;++r){
      float val = o[n][r] / lrow[r];
      Ob[(size_t)(q0 + lq*4 + r)*2048 + qh*64 + n*16 + l15] = f2b(val);
    }
}

extern "C" void kernel_launch(void* const* d_in, const int* in_sizes, int n_in,
                              void* d_out, int out_size, void* d_ws, size_t ws_size,
                              hipStream_t stream){
  const float* x      = (const float*)d_in[0];
  const int*   pos    = (const int*)d_in[1];
  const float* wq_swa = (const float*)d_in[2];
  const float* wk_swa = (const float*)d_in[3];
  const float* wv_swa = (const float*)d_in[4];
  const float* wq_hsa = (const float*)d_in[5];
  const float* wk_hsa = (const float*)d_in[6];
  const float* wv_hsa = (const float*)d_in[7];
  const float* qw     = (const float*)d_in[8];
  const float* kw     = (const float*)d_in[9];
  const float* wo     = (const float*)d_in[10];
  char* ws = (char*)d_ws;
  unsigned short* xb  = (unsigned short*)(ws);                 //  8 MB  [2048][2048]
  unsigned short* Wt  = (unsigned short*)(ws + 8388608);       // 12 MB  [3072][2048]
  unsigned short* WoT = (unsigned short*)(ws + 20971520);      //  8 MB  [2048][2048]
  float*          QKV = (float*)(ws + 29360128);               // 24 MB  [2048][3072]
  unsigned short* Qb  = (unsigned short*)(ws + 54525952);      //  8 MB  [32][2048][64]
  unsigned short* Kb  = (unsigned short*)(ws + 62914560);      //  2 MB  [8][2048][64]
  unsigned short* Vb  = (unsigned short*)(ws + 65011712);      //  2 MB  [8][2048][64]
  unsigned short* Ab  = (unsigned short*)(ws + 67108864);      //  8 MB  [2048][2048]
  float* out = (float*)d_out;

  k_cvt<<<4096, 256, 0, stream>>>(x, xb);
  k_transpose<<<dim3(24,32), 256, 0, stream>>>(wq_swa, Wt, 1536, 0);
  k_transpose<<<dim3(6,32),  256, 0, stream>>>(wk_swa, Wt, 384, 1536);
  k_transpose<<<dim3(6,32),  256, 0, stream>>>(wv_swa, Wt, 384, 1920);
  k_transpose<<<dim3(8,32),  256, 0, stream>>>(wq_hsa, Wt, 512, 2304);
  k_transpose<<<dim3(2,32),  256, 0, stream>>>(wk_hsa, Wt, 128, 2816);
  k_transpose<<<dim3(2,32),  256, 0, stream>>>(wv_hsa, Wt, 128, 2944);
  k_transpose<<<dim3(32,32), 256, 0, stream>>>(wo, WoT, 2048, 0);
  k_gemm_bt<<<dim3(24,16), 256, 0, stream>>>(xb, Wt, QKV, 2048, 3072, 2048);
  k_normrope<<<dim3(12,2048), 256, 0, stream>>>(QKV, pos, qw, kw, Qb, Kb, Vb);
  k_attn<<<dim3(128,8), 256, 0, stream>>>(Qb, Kb, Vb, Ab);
  k_gemm_bt<<<dim3(16,16), 256, 0, stream>>>(Ab, WoT, out, 2048, 2048, 2048);
}

// Round 10
// 308.705 us; speedup vs baseline: 1.2376x; 1.2376x over previous
//
#include <hip/hip_runtime.h>

#define S_LEN 2048
#define QKV_N 3072

typedef __bf16 bf16_t;
typedef bf16_t b16x8 __attribute__((ext_vector_type(8)));
typedef unsigned short u16x8 __attribute__((ext_vector_type(8)));
typedef float f32x4 __attribute__((ext_vector_type(4)));
typedef unsigned int u32;
typedef __attribute__((address_space(3))) u32 lds_u32;
typedef __attribute__((address_space(1))) const u32 g_u32;

__device__ __forceinline__ void gload16(void* l, const void* g){
  __builtin_amdgcn_global_load_lds((g_u32*)g, (lds_u32*)l, 16, 0, 0);
}

__device__ __forceinline__ unsigned short f2b(float f){
  u32 u = __builtin_bit_cast(u32, f);
  u += 0x7fffu + ((u >> 16) & 1u);
  return (unsigned short)(u >> 16);
}

// ---------------- elementwise f32 -> bf16 ----------------
__global__ __launch_bounds__(256) void k_cvt(const float* __restrict__ x,
                                             unsigned short* __restrict__ y){
  int i = (blockIdx.x * 256 + threadIdx.x) * 4;
  float4 v = *reinterpret_cast<const float4*>(x + i);
  ushort4 o; o.x = f2b(v.x); o.y = f2b(v.y); o.z = f2b(v.z); o.w = f2b(v.w);
  *reinterpret_cast<ushort4*>(y + i) = o;
}

// ------- transpose f32 [2048][Ncols] -> bf16 [nOff+Ncols][2048] -------
__global__ __launch_bounds__(256) void k_transpose(const float* __restrict__ W,
                                                   unsigned short* __restrict__ Wt,
                                                   int Ncols, int nOff){
  __shared__ float t[64][65];
  int tx = threadIdx.x & 15, ty = threadIdx.x >> 4;
  int n0 = blockIdx.x * 64, k0 = blockIdx.y * 64;
#pragma unroll
  for (int s2 = 0; s2 < 4; ++s2){
    int kr = ty + s2*16;
    float4 v = *reinterpret_cast<const float4*>(W + (size_t)(k0+kr)*Ncols + n0 + tx*4);
    t[kr][tx*4+0]=v.x; t[kr][tx*4+1]=v.y; t[kr][tx*4+2]=v.z; t[kr][tx*4+3]=v.w;
  }
  __syncthreads();
#pragma unroll
  for (int s2 = 0; s2 < 4; ++s2){
    int nr = ty + s2*16;
    ushort4 o;
    o.x = f2b(t[tx*4+0][nr]); o.y = f2b(t[tx*4+1][nr]);
    o.z = f2b(t[tx*4+2][nr]); o.w = f2b(t[tx*4+3][nr]);
    *reinterpret_cast<ushort4*>(Wt + (size_t)(nOff + n0 + nr)*2048 + k0 + tx*4) = o;
  }
}

// ------- V slice of QKV (f32) -> per-head transposed bf16 [8][64][2048] -------
__global__ __launch_bounds__(256) void k_vt(const float* __restrict__ QKV,
                                            unsigned short* __restrict__ Vt){
  __shared__ float t[64][65];
  int h = blockIdx.y, s0 = blockIdx.x * 64;
  int base = (h < 6) ? (1920 + 64*h) : (2944 + 64*(h-6));
  int tx = threadIdx.x & 15, ty = threadIdx.x >> 4;
#pragma unroll
  for (int it = 0; it < 4; ++it){
    int r = ty + it*16;
    float4 v = *reinterpret_cast<const float4*>(QKV + (size_t)(s0+r)*QKV_N + base + tx*4);
    t[r][tx*4+0]=v.x; t[r][tx*4+1]=v.y; t[r][tx*4+2]=v.z; t[r][tx*4+3]=v.w;
  }
  __syncthreads();
#pragma unroll
  for (int it = 0; it < 4; ++it){
    int d = ty + it*16;
    ushort4 o;
    o.x = f2b(t[tx*4+0][d]); o.y = f2b(t[tx*4+1][d]);
    o.z = f2b(t[tx*4+2][d]); o.w = f2b(t[tx*4+3][d]);
    *reinterpret_cast<ushort4*>(Vt + ((size_t)h*64 + d)*S_LEN + s0 + tx*4) = o;
  }
}

// ------- GEMM (m97 structure): C[M][N] f32 = A[M][K] bf16 * Bt[N][K]^T -------
__global__ __launch_bounds__(256) void k_gemm_bt(const unsigned short* __restrict__ A,
                                                const unsigned short* __restrict__ Bt,
                                                float* __restrict__ C,
                                                int M, int N, int K){
  __shared__ unsigned short As[128*32];
  __shared__ unsigned short Bs[128*32];
  const int tid = threadIdx.x, lane = tid & 63, w = tid >> 6;
  const int wr = w >> 1, wc = w & 1;
  const int l15 = lane & 15, lq = lane >> 4;
  const int rowA0 = blockIdx.y * 128, rowB0 = blockIdx.x * 128;
  const int scol = (lane & 3) * 8;  // staging lane -> 16B col
  f32x4 acc[4][4];
  f32x4 z4 = {0.f,0.f,0.f,0.f};
#pragma unroll
  for (int m=0;m<4;++m)
#pragma unroll
    for (int n=0;n<4;++n) acc[m][n] = z4;
  const int srow = lane >> 2;
  for (int k0 = 0; k0 < K; k0 += 32){
    __syncthreads();
#pragma unroll
    for (int i = 0; i < 2; ++i){
      int r = w*32 + i*16 + srow;
      gload16(&As[(w*32 + i*16)*32], A  + (size_t)(rowA0 + r)*K + k0 + scol);
      gload16(&Bs[(w*32 + i*16)*32], Bt + (size_t)(rowB0 + r)*K + k0 + scol);
    }
    __syncthreads();
    b16x8 af[4], bfr[4];
#pragma unroll
    for (int m=0;m<4;++m)
      af[m] = *reinterpret_cast<const b16x8*>(&As[(wr*64 + m*16 + l15)*32 + lq*8]);
#pragma unroll
    for (int n=0;n<4;++n)
      bfr[n] = *reinterpret_cast<const b16x8*>(&Bs[(wc*64 + n*16 + l15)*32 + lq*8]);
#pragma unroll
    for (int m=0;m<4;++m)
#pragma unroll
      for (int n=0;n<4;++n)
        acc[m][n] = __builtin_amdgcn_mfma_f32_16x16x32_bf16(af[m], bfr[n], acc[m][n], 0,0,0);
  }
  const int rB = rowA0 + wr*64, cB = rowB0 + wc*64;
#pragma unroll
  for (int m=0;m<4;++m)
#pragma unroll
    for (int n=0;n<4;++n)
#pragma unroll
      for (int r=0;r<4;++r)
        C[(size_t)(rB + m*16 + lq*4 + r)*N + cB + n*16 + l15] = acc[m][n][r];
}

// ------- per-head RMSNorm (+RoPE for SWA q/k; q pre-scaled by 0.125) -------
__global__ __launch_bounds__(256) void k_normrope(const float* __restrict__ QKV,
    const int* __restrict__ pos, const float* __restrict__ qw, const float* __restrict__ kw,
    unsigned short* __restrict__ Qb, unsigned short* __restrict__ Kb){
  int job = blockIdx.x * 4 + (threadIdx.x >> 6);
  int row = blockIdx.y;
  int d = threadIdx.x & 63;
  int srcCol; unsigned short* dst; const float* wn = qw; int rope = 0, qscale = 0;
  if (job < 24){ srcCol = job*64; dst = Qb + ((size_t)job*S_LEN + row)*64; rope = 1; qscale = 1; }
  else if (job < 30){ int h=job-24; srcCol = 1536 + h*64; dst = Kb + ((size_t)h*S_LEN + row)*64; wn = kw; rope = 1; }
  else if (job < 38){ int h=job-30; srcCol = 2304 + h*64; dst = Qb + ((size_t)(24+h)*S_LEN + row)*64; qscale = 1; }
  else { int h=job-38; srcCol = 2816 + h*64; dst = Kb + ((size_t)(6+h)*S_LEN + row)*64; wn = kw; }
  float x = QKV[(size_t)row*QKV_N + srcCol + d];
  float ss = x*x;
#pragma unroll
  for (int m=1;m<64;m<<=1) ss += __shfl_xor(ss, m);
  float y = x * rsqrtf(ss*(1.0f/64.0f) + 1e-6f) * wn[d];
  if (rope){
    int i = d & 31;
    float inv = expf(-(float)i * (13.815510557964274f * (1.0f/32.0f)));
    float ang = (float)pos[row] * inv;
    float c = cosf(ang), sn = sinf(ang);
    float partner = __shfl_xor(y, 32);
    y = (d < 32) ? (y*c - partner*sn) : (y*c + partner*sn);
  }
  if (qscale) y *= 0.125f;   // SCALE=D^-0.5, exact power of two in bf16
  dst[d] = f2b(y);
}

// ------- flash attention, swapped-QK^T (S^T = K·Q^T), KVBLK=64, QBLK=32/wave -------
// block: 4 waves = 4 q-heads of one GQA group, 32 q rows. 1D balanced grid.
__global__ __launch_bounds__(256,2) void k_attn(const unsigned short* __restrict__ Qb,
    const unsigned short* __restrict__ Kb, const unsigned short* __restrict__ Vtg,
    unsigned short* __restrict__ Ob){
  __shared__ unsigned short Ks[64*64];   // [kv][d] content XOR-swizzled (granule ^= row&7)
  __shared__ unsigned short Vs[64*64];   // [d][kv] content XOR-swizzled
  __shared__ unsigned short Pw[4][32*72]; // per-wave P[q][kv], pitch 72
  const int tid = threadIdx.x, lane = tid & 63, w = tid >> 6;
  const int l15 = lane & 15, lq = lane >> 4;
  int bid = blockIdx.x, kvi, qt;
  if (bid < 128){ kvi = 6 + (bid & 1); qt = 63 - (bid >> 1); }       // HSA, heavy-first
  else { int r = bid - 128; kvi = r % 6; qt = r / 6; }               // SWA
  const bool swa = (kvi < 6);
  const int qh = swa ? (kvi*4 + w) : (24 + (kvi-6)*4 + w);
  const int q0 = qt * 32;
  const unsigned short* Qh = Qb + (size_t)qh*S_LEN*64;
  const unsigned short* Kh = Kb + (size_t)kvi*S_LEN*64;
  const unsigned short* Vh = Vtg + (size_t)kvi*64*S_LEN;
  // Q fragments (B-frag of S^T): col = q = l15, k = lq*8+j
  b16x8 qf[2][2];
#pragma unroll
  for (int qm=0;qm<2;++qm)
#pragma unroll
    for (int h=0;h<2;++h)
      qf[qm][h] = *reinterpret_cast<const b16x8*>(Qh + (size_t)(q0+qm*16+l15)*64 + h*32 + lq*8);
  f32x4 z4 = {0.f,0.f,0.f,0.f};
  f32x4 o[4][2];  // O^T[d=dm*16+lq*4+r][q=qm*16+l15]
#pragma unroll
  for (int dm=0;dm<4;++dm){ o[dm][0]=z4; o[dm][1]=z4; }
  float mrun[2] = {-1e30f,-1e30f};
  float lrun[2] = {0.f,0.f};
  int jstart = 0;
  if (swa){ jstart = q0 - 511; if (jstart < 0) jstart = 0; jstart &= ~63; }
  const int jend = q0 + 32;
  for (int j0 = jstart; j0 < jend; j0 += 64){
    __syncthreads();
#pragma unroll
    for (int it = 0; it < 2; ++it){
      int slot = tid + it*256;
      int r = (slot >> 3), g = (slot & 7) ^ (r & 7);
      gload16(&Ks[(size_t)(it*256 + w*64)*8], Kh + (size_t)(j0 + r)*64 + g*8);
      gload16(&Vs[(size_t)(it*256 + w*64)*8], Vh + (size_t)r*S_LEN + j0 + g*8);
    }
    __syncthreads();
    // --- QK^T swapped: s[qm][ct] = S^T[kv=ct*16+lq*4+r][q=qm*16+l15]
    b16x8 kf[4][2];
#pragma unroll
    for (int ct=0;ct<4;++ct)
#pragma unroll
      for (int h=0;h<2;++h)
        kf[ct][h] = *reinterpret_cast<const b16x8*>(
          &Ks[(ct*16 + l15)*64 + (((h*4 + lq) ^ (l15 & 7)) << 3)]);
    f32x4 s[2][4];
#pragma unroll
    for (int qm=0;qm<2;++qm)
#pragma unroll
      for (int ct=0;ct<4;++ct){
        f32x4 acc = z4;
        acc = __builtin_amdgcn_mfma_f32_16x16x32_bf16(kf[ct][0], qf[qm][0], acc, 0,0,0);
        acc = __builtin_amdgcn_mfma_f32_16x16x32_bf16(kf[ct][1], qf[qm][1], acc, 0,0,0);
        s[qm][ct] = acc;
      }
    // --- online softmax per q-column (q = qm*16+l15, kv spread over lq only)
#pragma unroll
    for (int qm=0;qm<2;++qm){
      const int q = q0 + qm*16 + l15;
      const bool full = (j0 + 63 <= q0 + qm*16) &&
                        (!swa || (j0 >= q0 + qm*16 + 15 - 511));
      if (!full){
#pragma unroll
        for (int ct=0;ct<4;++ct)
#pragma unroll
          for (int r=0;r<4;++r){
            int kv = j0 + ct*16 + lq*4 + r;
            bool v = (kv <= q) && (!swa || (q - kv < 512));
            if (!v) s[qm][ct][r] = -1e30f;
          }
      }
      float pmax = s[qm][0][0];
#pragma unroll
      for (int ct=0;ct<4;++ct)
#pragma unroll
        for (int r=0;r<4;++r) pmax = fmaxf(pmax, s[qm][ct][r]);
      pmax = fmaxf(pmax, __shfl_xor(pmax, 16));
      pmax = fmaxf(pmax, __shfl_xor(pmax, 32));
      float mnew = fmaxf(mrun[qm], pmax);
      float f = __expf(mrun[qm] - mnew);
      mrun[qm] = mnew;
      float psum = 0.f;
#pragma unroll
      for (int ct=0;ct<4;++ct){
#pragma unroll
        for (int r=0;r<4;++r){
          float sv = s[qm][ct][r];
          float p = (sv > -0.5e30f) ? __expf(sv - mnew) : 0.f;
          s[qm][ct][r] = p;
          psum += p;
        }
#pragma unroll
        for (int u=0;u<2;++u){
          u32 dw = ((u32)f2b(s[qm][ct][2*u])) | (((u32)f2b(s[qm][ct][2*u+1])) << 16);
          *reinterpret_cast<u32*>(&Pw[w][(qm*16 + l15)*72 + ct*16 + lq*4 + 2*u]) = dw;
        }
      }
      psum += __shfl_xor(psum, 16);
      psum += __shfl_xor(psum, 32);
      lrun[qm] = lrun[qm]*f + psum;
#pragma unroll
      for (int dm=0;dm<4;++dm)
#pragma unroll
        for (int r=0;r<4;++r) o[dm][qm][r] *= f;
    }
    // --- PV swapped: O^T += V^T · P^T
    b16x8 vf[4][2];
#pragma unroll
    for (int dm=0;dm<4;++dm)
#pragma unroll
      for (int ks=0;ks<2;++ks)
        vf[dm][ks] = *reinterpret_cast<const b16x8*>(
          &Vs[(dm*16 + l15)*64 + (((ks*4 + lq) ^ (l15 & 7)) << 3)]);
    b16x8 pb[2][2];
#pragma unroll
    for (int qm=0;qm<2;++qm)
#pragma unroll
      for (int ks=0;ks<2;++ks)
        pb[qm][ks] = *reinterpret_cast<const b16x8*>(&Pw[w][(qm*16 + l15)*72 + ks*32 + lq*8]);
#pragma unroll
    for (int dm=0;dm<4;++dm)
#pragma unroll
      for (int qm=0;qm<2;++qm){
        o[dm][qm] = __builtin_amdgcn_mfma_f32_16x16x32_bf16(vf[dm][0], pb[qm][0], o[dm][qm], 0,0,0);
        o[dm][qm] = __builtin_amdgcn_mfma_f32_16x16x32_bf16(vf[dm][1], pb[qm][1], o[dm][qm], 0,0,0);
      }
  }
  // --- epilogue: O[q][d] = O^T/l
#pragma unroll
  for (int qm=0;qm<2;++qm){
    float inv = 1.0f / lrun[qm];
    const size_t rowb = (size_t)(q0 + qm*16 + l15) * 2048 + qh*64;
#pragma unroll
    for (int dm=0;dm<4;++dm){
      ushort4 ov;
      ov.x = f2b(o[dm][qm][0]*inv); ov.y = f2b(o[dm][qm][1]*inv);
      ov.z = f2b(o[dm][qm][2]*inv); ov.w = f2b(o[dm][qm][3]*inv);
      *reinterpret_cast<ushort4*>(Ob + rowb + dm*16 + lq*4) = ov;
    }
  }
}

extern "C" void kernel_launch(void* const* d_in, const int* in_sizes, int n_in,
                              void* d_out, int out_size, void* d_ws, size_t ws_size,
                              hipStream_t stream){
  const float* x      = (const float*)d_in[0];
  const int*   pos    = (const int*)d_in[1];
  const float* wq_swa = (const float*)d_in[2];
  const float* wk_swa = (const float*)d_in[3];
  const float* wv_swa = (const float*)d_in[4];
  const float* wq_hsa = (const float*)d_in[5];
  const float* wk_hsa = (const float*)d_in[6];
  const float* wv_hsa = (const float*)d_in[7];
  const float* qw     = (const float*)d_in[8];
  const float* kw     = (const float*)d_in[9];
  const float* wo     = (const float*)d_in[10];
  char* ws = (char*)d_ws;
  unsigned short* xb  = (unsigned short*)(ws);                 //  8 MB
  unsigned short* Wt  = (unsigned short*)(ws + 8388608);       // 12 MB
  unsigned short* WoT = (unsigned short*)(ws + 20971520);      //  8 MB
  float*          QKV = (float*)(ws + 29360128);               // 24 MB
  unsigned short* Qb  = (unsigned short*)(ws + 54525952);      //  8 MB [32][2048][64]
  unsigned short* Kb  = (unsigned short*)(ws + 62914560);      //  2 MB [8][2048][64]
  unsigned short* Vtg = (unsigned short*)(ws + 65011712);      //  2 MB [8][64][2048]
  unsigned short* Ab  = (unsigned short*)(ws + 67108864);      //  8 MB [2048][2048]
  float* out = (float*)d_out;

  k_cvt<<<4096, 256, 0, stream>>>(x, xb);
  k_transpose<<<dim3(24,32), 256, 0, stream>>>(wq_swa, Wt, 1536, 0);
  k_transpose<<<dim3(6,32),  256, 0, stream>>>(wk_swa, Wt, 384, 1536);
  k_transpose<<<dim3(6,32),  256, 0, stream>>>(wv_swa, Wt, 384, 1920);
  k_transpose<<<dim3(8,32),  256, 0, stream>>>(wq_hsa, Wt, 512, 2304);
  k_transpose<<<dim3(2,32),  256, 0, stream>>>(wk_hsa, Wt, 128, 2816);
  k_transpose<<<dim3(2,32),  256, 0, stream>>>(wv_hsa, Wt, 128, 2944);
  k_transpose<<<dim3(32,32), 256, 0, stream>>>(wo, WoT, 2048, 0);
  k_gemm_bt<<<dim3(24,16), 256, 0, stream>>>(xb, Wt, QKV, 2048, 3072, 2048);
  k_normrope<<<dim3(10,2048), 256, 0, stream>>>(QKV, pos, qw, kw, Qb, Kb);
  k_vt<<<dim3(32,8), 256, 0, stream>>>(QKV, Vtg);
  k_attn<<<512, 256, 0, stream>>>(Qb, Kb, Vtg, Ab);
  k_gemm_bt<<<dim3(16,16), 256, 0, stream>>>(Ab, WoT, out, 2048, 2048, 2048);
}

// Round 12
// 300.857 us; speedup vs baseline: 1.2699x; 1.0261x over previous
//
#include <hip/hip_runtime.h>

#define S_LEN 2048
#define QKV_N 3072

typedef __bf16 bf16_t;
typedef bf16_t b16x8 __attribute__((ext_vector_type(8)));
typedef float f32x4 __attribute__((ext_vector_type(4)));
typedef unsigned int u32;
typedef __attribute__((address_space(3))) u32 lds_u32;
typedef __attribute__((address_space(1))) const u32 g_u32;

__device__ __forceinline__ void gload16(void* l, const void* g){
  __builtin_amdgcn_global_load_lds((g_u32*)g, (lds_u32*)l, 16, 0, 0);
}

__device__ __forceinline__ unsigned short f2b(float f){
  u32 u = __builtin_bit_cast(u32, f);
  u += 0x7fffu + ((u >> 16) & 1u);
  return (unsigned short)(u >> 16);
}

// ---------------- elementwise f32 -> bf16 ----------------
__global__ __launch_bounds__(256) void k_cvt(const float* __restrict__ x,
                                             unsigned short* __restrict__ y){
  int i = (blockIdx.x * 256 + threadIdx.x) * 4;
  float4 v = *reinterpret_cast<const float4*>(x + i);
  ushort4 o; o.x = f2b(v.x); o.y = f2b(v.y); o.z = f2b(v.z); o.w = f2b(v.w);
  *reinterpret_cast<ushort4*>(y + i) = o;
}

// ------- transpose f32 [2048][Ncols] -> bf16 [nOff+Ncols][2048] -------
__global__ __launch_bounds__(256) void k_transpose(const float* __restrict__ W,
                                                   unsigned short* __restrict__ Wt,
                                                   int Ncols, int nOff){
  __shared__ float t[64][65];
  int tx = threadIdx.x & 15, ty = threadIdx.x >> 4;
  int n0 = blockIdx.x * 64, k0 = blockIdx.y * 64;
#pragma unroll
  for (int s2 = 0; s2 < 4; ++s2){
    int kr = ty + s2*16;
    float4 v = *reinterpret_cast<const float4*>(W + (size_t)(k0+kr)*Ncols + n0 + tx*4);
    t[kr][tx*4+0]=v.x; t[kr][tx*4+1]=v.y; t[kr][tx*4+2]=v.z; t[kr][tx*4+3]=v.w;
  }
  __syncthreads();
#pragma unroll
  for (int s2 = 0; s2 < 4; ++s2){
    int nr = ty + s2*16;
    ushort4 o;
    o.x = f2b(t[tx*4+0][nr]); o.y = f2b(t[tx*4+1][nr]);
    o.z = f2b(t[tx*4+2][nr]); o.w = f2b(t[tx*4+3][nr]);
    *reinterpret_cast<ushort4*>(Wt + (size_t)(nOff + n0 + nr)*2048 + k0 + tx*4) = o;
  }
}

// ------- fused transpose of all 6 QKV weights -> Wt [3072][2048] -------
// segment boundaries (1536,1920,2304,2816,2944) are all multiples of 64,
// so each 64-wide n-tile lies in exactly one source weight.
__global__ __launch_bounds__(256) void k_transpose_qkv(
    const float* __restrict__ wq_s, const float* __restrict__ wk_s,
    const float* __restrict__ wv_s, const float* __restrict__ wq_h,
    const float* __restrict__ wk_h, const float* __restrict__ wv_h,
    unsigned short* __restrict__ Wt){
  __shared__ float t[64][65];
  int n0 = blockIdx.x * 64, k0 = blockIdx.y * 64;
  const float* W; int Ncols, base;
  if      (n0 < 1536){ W = wq_s; Ncols = 1536; base = 0;    }
  else if (n0 < 1920){ W = wk_s; Ncols = 384;  base = 1536; }
  else if (n0 < 2304){ W = wv_s; Ncols = 384;  base = 1920; }
  else if (n0 < 2816){ W = wq_h; Ncols = 512;  base = 2304; }
  else if (n0 < 2944){ W = wk_h; Ncols = 128;  base = 2816; }
  else               { W = wv_h; Ncols = 128;  base = 2944; }
  int nl = n0 - base;
  int tx = threadIdx.x & 15, ty = threadIdx.x >> 4;
#pragma unroll
  for (int s2 = 0; s2 < 4; ++s2){
    int kr = ty + s2*16;
    float4 v = *reinterpret_cast<const float4*>(W + (size_t)(k0+kr)*Ncols + nl + tx*4);
    t[kr][tx*4+0]=v.x; t[kr][tx*4+1]=v.y; t[kr][tx*4+2]=v.z; t[kr][tx*4+3]=v.w;
  }
  __syncthreads();
#pragma unroll
  for (int s2 = 0; s2 < 4; ++s2){
    int nr = ty + s2*16;
    ushort4 o;
    o.x = f2b(t[tx*4+0][nr]); o.y = f2b(t[tx*4+1][nr]);
    o.z = f2b(t[tx*4+2][nr]); o.w = f2b(t[tx*4+3][nr]);
    *reinterpret_cast<ushort4*>(Wt + (size_t)(n0 + nr)*2048 + k0 + tx*4) = o;
  }
}

// ------- V slice of QKV (f32) -> per-head transposed bf16 [8][64][2048] -------
__global__ __launch_bounds__(256) void k_vt(const float* __restrict__ QKV,
                                            unsigned short* __restrict__ Vt){
  __shared__ float t[64][65];
  int h = blockIdx.y, s0 = blockIdx.x * 64;
  int base = (h < 6) ? (1920 + 64*h) : (2944 + 64*(h-6));
  int tx = threadIdx.x & 15, ty = threadIdx.x >> 4;
#pragma unroll
  for (int it = 0; it < 4; ++it){
    int r = ty + it*16;
    float4 v = *reinterpret_cast<const float4*>(QKV + (size_t)(s0+r)*QKV_N + base + tx*4);
    t[r][tx*4+0]=v.x; t[r][tx*4+1]=v.y; t[r][tx*4+2]=v.z; t[r][tx*4+3]=v.w;
  }
  __syncthreads();
#pragma unroll
  for (int it = 0; it < 4; ++it){
    int d = ty + it*16;
    ushort4 o;
    o.x = f2b(t[tx*4+0][d]); o.y = f2b(t[tx*4+1][d]);
    o.z = f2b(t[tx*4+2][d]); o.w = f2b(t[tx*4+3][d]);
    *reinterpret_cast<ushort4*>(Vt + ((size_t)h*64 + d)*S_LEN + s0 + tx*4) = o;
  }
}

// ------- GEMM, 2-phase prefetch: C[M][N] f32 = A[M][K] bf16 * Bt[N][K]^T -------
// stage tile k0+32 into buf^1 BEFORE computing buf; single barrier per K-step
// (its implicit vmcnt(0)+lgkmcnt(0) drain is the required fence).
__global__ __launch_bounds__(256) void k_gemm_bt(const unsigned short* __restrict__ A,
                                                const unsigned short* __restrict__ Bt,
                                                float* __restrict__ C,
                                                int M, int N, int K){
  __shared__ unsigned short As[2][128*32];
  __shared__ unsigned short Bs[2][128*32];
  const int tid = threadIdx.x, lane = tid & 63, w = tid >> 6;
  const int wr = w >> 1, wc = w & 1;
  const int l15 = lane & 15, lq = lane >> 4;
  const int rowA0 = blockIdx.y * 128, rowB0 = blockIdx.x * 128;
  const int srow = lane >> 2, scol = (lane & 3) * 8;
  f32x4 acc[4][4];
  f32x4 z4 = {0.f,0.f,0.f,0.f};
#pragma unroll
  for (int m=0;m<4;++m)
#pragma unroll
    for (int n=0;n<4;++n) acc[m][n] = z4;
  // prologue: stage k0=0 into buf 0
#pragma unroll
  for (int i = 0; i < 2; ++i){
    int r = w*32 + i*16 + srow;
    gload16(&As[0][(w*32 + i*16)*32], A  + (size_t)(rowA0 + r)*K + scol);
    gload16(&Bs[0][(w*32 + i*16)*32], Bt + (size_t)(rowB0 + r)*K + scol);
  }
  __syncthreads();
  int cur = 0;
  for (int k0 = 0; k0 < K; k0 += 32){
    if (k0 + 32 < K){
#pragma unroll
      for (int i = 0; i < 2; ++i){
        int r = w*32 + i*16 + srow;
        gload16(&As[cur^1][(w*32 + i*16)*32], A  + (size_t)(rowA0 + r)*K + k0 + 32 + scol);
        gload16(&Bs[cur^1][(w*32 + i*16)*32], Bt + (size_t)(rowB0 + r)*K + k0 + 32 + scol);
      }
    }
    b16x8 af[4], bfr[4];
#pragma unroll
    for (int m=0;m<4;++m)
      af[m] = *reinterpret_cast<const b16x8*>(&As[cur][(wr*64 + m*16 + l15)*32 + lq*8]);
#pragma unroll
    for (int n=0;n<4;++n)
      bfr[n] = *reinterpret_cast<const b16x8*>(&Bs[cur][(wc*64 + n*16 + l15)*32 + lq*8]);
#pragma unroll
    for (int m=0;m<4;++m)
#pragma unroll
      for (int n=0;n<4;++n)
        acc[m][n] = __builtin_amdgcn_mfma_f32_16x16x32_bf16(af[m], bfr[n], acc[m][n], 0,0,0);
    __syncthreads();
    cur ^= 1;
  }
  const int rB = rowA0 + wr*64, cB = rowB0 + wc*64;
#pragma unroll
  for (int m=0;m<4;++m)
#pragma unroll
    for (int n=0;n<4;++n)
#pragma unroll
      for (int r=0;r<4;++r)
        C[(size_t)(rB + m*16 + lq*4 + r)*N + cB + n*16 + l15] = acc[m][n][r];
}

// ------- per-head RMSNorm (+RoPE for SWA q/k; q pre-scaled by 0.125) -------
__global__ __launch_bounds__(256) void k_normrope(const float* __restrict__ QKV,
    const int* __restrict__ pos, const float* __restrict__ qw, const float* __restrict__ kw,
    unsigned short* __restrict__ Qb, unsigned short* __restrict__ Kb){
  int job = blockIdx.x * 4 + (threadIdx.x >> 6);
  int row = blockIdx.y;
  int d = threadIdx.x & 63;
  int srcCol; unsigned short* dst; const float* wn = qw; int rope = 0, qscale = 0;
  if (job < 24){ srcCol = job*64; dst = Qb + ((size_t)job*S_LEN + row)*64; rope = 1; qscale = 1; }
  else if (job < 30){ int h=job-24; srcCol = 1536 + h*64; dst = Kb + ((size_t)h*S_LEN + row)*64; wn = kw; rope = 1; }
  else if (job < 38){ int h=job-30; srcCol = 2304 + h*64; dst = Qb + ((size_t)(24+h)*S_LEN + row)*64; qscale = 1; }
  else { int h=job-38; srcCol = 2816 + h*64; dst = Kb + ((size_t)(6+h)*S_LEN + row)*64; wn = kw; }
  float x = QKV[(size_t)row*QKV_N + srcCol + d];
  float ss = x*x;
#pragma unroll
  for (int m=1;m<64;m<<=1) ss += __shfl_xor(ss, m);
  float y = x * rsqrtf(ss*(1.0f/64.0f) + 1e-6f) * wn[d];
  if (rope){
    int i = d & 31;
    float inv = expf(-(float)i * (13.815510557964274f * (1.0f/32.0f)));
    float ang = (float)pos[row] * inv;
    float c = cosf(ang), sn = sinf(ang);
    float partner = __shfl_xor(y, 32);
    y = (d < 32) ? (y*c - partner*sn) : (y*c + partner*sn);
  }
  if (qscale) y *= 0.125f;   // SCALE=D^-0.5, exact power of two in bf16
  dst[d] = f2b(y);
}

// ------- flash attention, swapped-QK^T, KVBLK=32 double-buffered 2-phase -------
// block: 4 waves = 4 q-heads of one GQA group, 32 q rows.
// LDS 26.6 KB -> 3+ blocks/CU; prefetch next K/V tile before computing current.
__global__ __launch_bounds__(256,3) void k_attn(const unsigned short* __restrict__ Qb,
    const unsigned short* __restrict__ Kb, const unsigned short* __restrict__ Vtg,
    unsigned short* __restrict__ Ob){
  __shared__ unsigned short Ks[2][32*64];  // [buf][kv][d], granule ^= kv&7
  __shared__ unsigned short Vs[2][64*32];  // [buf][d][kv], granule ^= d&3
  __shared__ unsigned short Pw[4][32*40];  // per-wave P[q][kv], pitch 40
  const int tid = threadIdx.x, lane = tid & 63, w = tid >> 6;
  const int l15 = lane & 15, lq = lane >> 4;
  int bid = blockIdx.x, kvi, qt;
  if (bid < 128){ kvi = 6 + (bid & 1); qt = 63 - (bid >> 1); }       // HSA, heavy-first
  else { int r = bid - 128; kvi = r % 6; qt = r / 6; }               // SWA
  const bool swa = (kvi < 6);
  const int qh = swa ? (kvi*4 + w) : (24 + (kvi-6)*4 + w);
  const int q0 = qt * 32;
  const unsigned short* Qh = Qb + (size_t)qh*S_LEN*64;
  const unsigned short* Kh = Kb + (size_t)kvi*S_LEN*64;
  const unsigned short* Vh = Vtg + (size_t)kvi*64*S_LEN;
  b16x8 qf[2][2];
#pragma unroll
  for (int qm=0;qm<2;++qm)
#pragma unroll
    for (int h=0;h<2;++h)
      qf[qm][h] = *reinterpret_cast<const b16x8*>(Qh + (size_t)(q0+qm*16+l15)*64 + h*32 + lq*8);
  f32x4 z4 = {0.f,0.f,0.f,0.f};
  f32x4 o[4][2];  // O^T[d=dm*16+lq*4+r][q=qm*16+l15]
#pragma unroll
  for (int dm=0;dm<4;++dm){ o[dm][0]=z4; o[dm][1]=z4; }
  float mrun[2] = {-1e30f,-1e30f};
  float lrun[2] = {0.f,0.f};
  int jstart = 0;
  if (swa){ jstart = q0 - 511; if (jstart < 0) jstart = 0; jstart &= ~31; }
  const int jend = q0 + 32;
  // staging: slot == tid; K: 32 rows x 8 granules; V: 64 rows x 4 granules.
  const int rK = tid >> 3, gK = ((tid & 7) ^ (rK & 7)) * 8;
  const int dV = tid >> 2, gV = ((tid & 3) ^ (dV & 3)) * 8;
  const int ldsW = w * 512;   // wave-uniform LDS base (shorts): 64 slots * 8
  // prologue: stage first tile into buf 0
  gload16(&Ks[0][ldsW], Kh + (size_t)(jstart + rK)*64 + gK);
  gload16(&Vs[0][ldsW], Vh + (size_t)dV*S_LEN + jstart + gV);
  __syncthreads();
  int cur = 0;
  for (int j0 = jstart; j0 < jend; j0 += 32){
    if (j0 + 32 < jend){   // prefetch next tile into the other buffer
      gload16(&Ks[cur^1][ldsW], Kh + (size_t)(j0 + 32 + rK)*64 + gK);
      gload16(&Vs[cur^1][ldsW], Vh + (size_t)dV*S_LEN + j0 + 32 + gV);
    }
    // --- QK^T swapped: s[qm][ct] = S^T[kv=ct*16+lq*4+r][q=qm*16+l15]
    b16x8 kf[2][2];
#pragma unroll
    for (int ct=0;ct<2;++ct)
#pragma unroll
      for (int h=0;h<2;++h)
        kf[ct][h] = *reinterpret_cast<const b16x8*>(
          &Ks[cur][(ct*16 + l15)*64 + (((h*4 + lq) ^ (l15 & 7)) << 3)]);
    f32x4 s[2][2];
#pragma unroll
    for (int qm=0;qm<2;++qm)
#pragma unroll
      for (int ct=0;ct<2;++ct){
        f32x4 acc = z4;
        acc = __builtin_amdgcn_mfma_f32_16x16x32_bf16(kf[ct][0], qf[qm][0], acc, 0,0,0);
        acc = __builtin_amdgcn_mfma_f32_16x16x32_bf16(kf[ct][1], qf[qm][1], acc, 0,0,0);
        s[qm][ct] = acc;
      }
    // --- online softmax per q-column
#pragma unroll
    for (int qm=0;qm<2;++qm){
      const int q = q0 + qm*16 + l15;
      const bool full = (j0 + 31 <= q0 + qm*16) &&
                        (!swa || (j0 >= q0 + qm*16 + 15 - 511));
      if (!full){
#pragma unroll
        for (int ct=0;ct<2;++ct)
#pragma unroll
          for (int r=0;r<4;++r){
            int kv = j0 + ct*16 + lq*4 + r;
            bool v = (kv <= q) && (!swa || (q - kv < 512));
            if (!v) s[qm][ct][r] = -1e30f;
          }
      }
      float pmax = s[qm][0][0];
#pragma unroll
      for (int ct=0;ct<2;++ct)
#pragma unroll
        for (int r=0;r<4;++r) pmax = fmaxf(pmax, s[qm][ct][r]);
      pmax = fmaxf(pmax, __shfl_xor(pmax, 16));
      pmax = fmaxf(pmax, __shfl_xor(pmax, 32));
      float mnew = fmaxf(mrun[qm], pmax);
      float f = __expf(mrun[qm] - mnew);
      mrun[qm] = mnew;
      float psum = 0.f;
#pragma unroll
      for (int ct=0;ct<2;++ct){
#pragma unroll
        for (int r=0;r<4;++r){
          float sv = s[qm][ct][r];
          float p = (sv > -0.5e30f) ? __expf(sv - mnew) : 0.f;
          s[qm][ct][r] = p;
          psum += p;
        }
#pragma unroll
        for (int u=0;u<2;++u){
          u32 dw = ((u32)f2b(s[qm][ct][2*u])) | (((u32)f2b(s[qm][ct][2*u+1])) << 16);
          *reinterpret_cast<u32*>(&Pw[w][(qm*16 + l15)*40 + ct*16 + lq*4 + 2*u]) = dw;
        }
      }
      psum += __shfl_xor(psum, 16);
      psum += __shfl_xor(psum, 32);
      lrun[qm] = lrun[qm]*f + psum;
#pragma unroll
      for (int dm=0;dm<4;++dm)
#pragma unroll
        for (int r=0;r<4;++r) o[dm][qm][r] *= f;
    }
    // --- PV swapped: O^T += V^T · P^T (one 32-deep MFMA per (dm,qm))
    b16x8 vf[4];
#pragma unroll
    for (int dm=0;dm<4;++dm)
      vf[dm] = *reinterpret_cast<const b16x8*>(
        &Vs[cur][(dm*16 + l15)*32 + ((lq ^ (l15 & 3)) << 3)]);
    b16x8 pb[2];
#pragma unroll
    for (int qm=0;qm<2;++qm)
      pb[qm] = *reinterpret_cast<const b16x8*>(&Pw[w][(qm*16 + l15)*40 + lq*8]);
#pragma unroll
    for (int dm=0;dm<4;++dm)
#pragma unroll
      for (int qm=0;qm<2;++qm)
        o[dm][qm] = __builtin_amdgcn_mfma_f32_16x16x32_bf16(vf[dm], pb[qm], o[dm][qm], 0,0,0);
    __syncthreads();   // drains vmcnt (next tile landed) + lgkm (reads done)
    cur ^= 1;
  }
  // --- epilogue: O[q][d] = O^T/l
#pragma unroll
  for (int qm=0;qm<2;++qm){
    float inv = 1.0f / lrun[qm];
    const size_t rowb = (size_t)(q0 + qm*16 + l15) * 2048 + qh*64;
#pragma unroll
    for (int dm=0;dm<4;++dm){
      ushort4 ov;
      ov.x = f2b(o[dm][qm][0]*inv); ov.y = f2b(o[dm][qm][1]*inv);
      ov.z = f2b(o[dm][qm][2]*inv); ov.w = f2b(o[dm][qm][3]*inv);
      *reinterpret_cast<ushort4*>(Ob + rowb + dm*16 + lq*4) = ov;
    }
  }
}

extern "C" void kernel_launch(void* const* d_in, const int* in_sizes, int n_in,
                              void* d_out, int out_size, void* d_ws, size_t ws_size,
                              hipStream_t stream){
  const float* x      = (const float*)d_in[0];
  const int*   pos    = (const int*)d_in[1];
  const float* wq_swa = (const float*)d_in[2];
  const float* wk_swa = (const float*)d_in[3];
  const float* wv_swa = (const float*)d_in[4];
  const float* wq_hsa = (const float*)d_in[5];
  const float* wk_hsa = (const float*)d_in[6];
  const float* wv_hsa = (const float*)d_in[7];
  const float* qw     = (const float*)d_in[8];
  const float* kw     = (const float*)d_in[9];
  const float* wo     = (const float*)d_in[10];
  char* ws = (char*)d_ws;
  unsigned short* xb  = (unsigned short*)(ws);                 //  8 MB
  unsigned short* Wt  = (unsigned short*)(ws + 8388608);       // 12 MB
  unsigned short* WoT = (unsigned short*)(ws + 20971520);      //  8 MB
  float*          QKV = (float*)(ws + 29360128);               // 24 MB
  unsigned short* Qb  = (unsigned short*)(ws + 54525952);      //  8 MB [32][2048][64]
  unsigned short* Kb  = (unsigned short*)(ws + 62914560);      //  2 MB [8][2048][64]
  unsigned short* Vtg = (unsigned short*)(ws + 65011712);      //  2 MB [8][64][2048]
  unsigned short* Ab  = (unsigned short*)(ws + 67108864);      //  8 MB [2048][2048]
  float* out = (float*)d_out;

  k_cvt<<<4096, 256, 0, stream>>>(x, xb);
  k_transpose_qkv<<<dim3(48,32), 256, 0, stream>>>(wq_swa, wk_swa, wv_swa,
                                                   wq_hsa, wk_hsa, wv_hsa, Wt);
  k_transpose<<<dim3(32,32), 256, 0, stream>>>(wo, WoT, 2048, 0);
  k_gemm_bt<<<dim3(24,16), 256, 0, stream>>>(xb, Wt, QKV, 2048, 3072, 2048);
  k_normrope<<<dim3(10,2048), 256, 0, stream>>>(QKV, pos, qw, kw, Qb, Kb);
  k_vt<<<dim3(32,8), 256, 0, stream>>>(QKV, Vtg);
  k_attn<<<512, 256, 0, stream>>>(Qb, Kb, Vtg, Ab);
  k_gemm_bt<<<dim3(16,16), 256, 0, stream>>>(Ab, WoT, out, 2048, 2048, 2048);
}